// Round 1
// baseline (9015.871 us; speedup 1.0000x reference)
//
#include <hip/hip_runtime.h>
#include <math.h>

#define B_ 64
#define T_ 128
#define INDIM 300
#define D_ 64
#define C_ 10
#define BETA_ 0.8f

static __device__ __forceinline__ float sigmoidf_(float x) { return 1.0f / (1.0f + expf(-x)); }

static __device__ __forceinline__ float wave_sum(float v) {
    #pragma unroll
    for (int off = 32; off > 0; off >>= 1) v += __shfl_down(v, off);
    return v;
}

// C[2tr+i][4tc+j] = sum_k P[k][2tr+i] * Q[k][4tc+j]
// Pb = P + rloc (LDS, row stride 64), Qb = Q + 4*tc (global or LDS, row stride 64)
static __device__ __forceinline__ void gemm64(const float* __restrict__ Pb,
                                              const float* __restrict__ Qb,
                                              float acc[2][4]) {
    #pragma unroll
    for (int i = 0; i < 2; ++i)
        #pragma unroll
        for (int j = 0; j < 4; ++j) acc[i][j] = 0.f;
    #pragma unroll 8
    for (int k = 0; k < 64; ++k) {
        const float2 pv = *reinterpret_cast<const float2*>(Pb + (size_t)k * 64);
        const float4 qv = *reinterpret_cast<const float4*>(Qb + (size_t)k * 64);
        acc[0][0] = fmaf(pv.x, qv.x, acc[0][0]);
        acc[0][1] = fmaf(pv.x, qv.y, acc[0][1]);
        acc[0][2] = fmaf(pv.x, qv.z, acc[0][2]);
        acc[0][3] = fmaf(pv.x, qv.w, acc[0][3]);
        acc[1][0] = fmaf(pv.y, qv.x, acc[1][0]);
        acc[1][1] = fmaf(pv.y, qv.y, acc[1][1]);
        acc[1][2] = fmaf(pv.y, qv.z, acc[1][2]);
        acc[1][3] = fmaf(pv.y, qv.w, acc[1][3]);
    }
}

// ---------------- Kernel A: projections + s + u = Ux @ s -------------------
__global__ __launch_bounds__(64) void proj_kernel(
    const float* __restrict__ x, const float* __restrict__ amp_w,
    const float* __restrict__ amp_b, const float* __restrict__ phase_w,
    const float* __restrict__ phase_b, const float* __restrict__ Ux,
    float* __restrict__ u_out) {
    __shared__ float xr[INDIM];
    __shared__ float s_r[D_], s_i[D_];
    const int bt = blockIdx.x;            // bt = b*T + t  (x is [B][T][IN])
    const int b = bt / T_, t = bt % T_;
    const float* xrow = x + (size_t)bt * INDIM;
    for (int i = threadIdx.x; i < INDIM; i += 64) xr[i] = xrow[i];
    __syncthreads();
    const int d = threadIdx.x;
    float a = amp_b[d], p = phase_b[d];
    for (int k = 0; k < INDIM; ++k) {
        float xv = xr[k];
        a = fmaf(xv, amp_w[k * D_ + d], a);
        p = fmaf(xv, phase_w[k * D_ + d], p);
    }
    float sq = a * a;
    #pragma unroll
    for (int off = 32; off > 0; off >>= 1) sq += __shfl_xor(sq, off);
    float an = a / sqrtf(sq);
    s_r[d] = an * cosf(p);
    s_i[d] = an * sinf(p);
    __syncthreads();
    float ur = 0.f, ui = 0.f;
    const float* Uxrow = Ux + d * D_;
    for (int e = 0; e < D_; ++e) {
        float uv = Uxrow[e];
        ur = fmaf(uv, s_r[e], ur);
        ui = fmaf(uv, s_i[e], ui);
    }
    float* ub = u_out + ((size_t)t * B_ + b) * 128;
    ub[d] = ur;
    ub[64 + d] = ui;
}

// ---------------- Kernel B: transposes + measurement vector prep ------------
__global__ __launch_bounds__(256) void setup_kernel(
    const float* __restrict__ Uh, const float* __restrict__ Ux,
    const float* __restrict__ W, const float* __restrict__ meas,
    float* __restrict__ UhT, float* __restrict__ UxT, float* __restrict__ AB2) {
    const int tid = threadIdx.x;
    for (int i = tid; i < D_ * D_; i += 256) {
        int k = i >> 6, r = i & 63;
        UhT[i] = Uh[r * D_ + k];
        UxT[i] = Ux[r * D_ + k];
    }
    __shared__ float invn[C_];
    if (tid < C_) {
        float s = 0.f;
        for (int j = 0; j < C_; ++j) {
            float vr = meas[(tid * C_ + j) * 2], vi = meas[(tid * C_ + j) * 2 + 1];
            s += vr * vr + vi * vi;
        }
        invn[tid] = 1.0f / sqrtf(s);
    }
    __syncthreads();
    // AB2[d][c] (row stride 32): c<10: a_c = W v̂r_c ; c<20: b = W v̂i ; c<30: W cols ; else 0
    for (int i = tid; i < D_ * 32; i += 256) {
        int dd = i >> 5, c = i & 31;
        float v = 0.f;
        if (c < C_) {
            float acc = 0.f;
            for (int j = 0; j < C_; ++j) acc = fmaf(W[dd * C_ + j], meas[(c * C_ + j) * 2], acc);
            v = acc * invn[c];
        } else if (c < 2 * C_) {
            int k = c - C_;
            float acc = 0.f;
            for (int j = 0; j < C_; ++j) acc = fmaf(W[dd * C_ + j], meas[(k * C_ + j) * 2 + 1], acc);
            v = acc * invn[k];
        } else if (c < 3 * C_) {
            v = W[dd * C_ + (c - 2 * C_)];
        }
        AB2[i] = v;
    }
}

// ---------------- Kernel C: fused 2-layer scan + dense + measurement --------
__global__ __launch_bounds__(1024) void qrnn_kernel(
    const float* __restrict__ u_in,   // [T][B][128] : u_r(64) | u_i(64)
    const float* __restrict__ UhT_g,  // [64][64]
    const float* __restrict__ UxT_g,  // [64][64]
    const float* __restrict__ AB2_g,  // [64][32]
    const float* __restrict__ W_g,    // [64][10]
    const float* __restrict__ cell_lambda, const float* __restrict__ dense_lambda,
    float* __restrict__ out)          // [B][T][C]
{
    __shared__ __align__(16) float h1r[4096], h1i[4096], h2r[4096], h2i[4096];
    __shared__ __align__(16) float Nr[4096], Ni[4096];
    __shared__ __align__(16) float Tb[8192];   // 128 x 64 stacked intermediate / Z-alias
    __shared__ float scr[16];

    const int tid = threadIdx.x;
    const int b = blockIdx.x;
    const float lam = sigmoidf_(cell_lambda[0]);
    const float dlam = sigmoidf_(dense_lambda[0]);

    for (int i = tid; i < 4096; i += 1024) {
        float v = ((i & 63) == (i >> 6)) ? 0.015625f : 0.0f;  // I/64
        h1r[i] = v; h2r[i] = v; h1i[i] = 0.f; h2i[i] = 0.f;
    }
    __syncthreads();

    const int tr = tid >> 4;            // 0..63 -> rows 2tr, 2tr+1 (of 128)
    const int tc = tid & 15;            // cols 4tc..4tc+3
    const int half = tr >> 5;           // 0: real part rows, 1: imag part rows
    const int rloc = (tr & 31) << 1;    // local row within half
    const int cbase = tc << 2;

    // stage1: Tb <- [hR | hI]^T-stacked conj intermediate = GEMM(h, Q)
    auto stage1 = [&](const float* hR, const float* hI, const float* Qg) {
        const float* Pb = (half ? hI : hR) + rloc;
        float acc[2][4];
        gemm64(Pb, Qg + cbase, acc);
        float* o = Tb + (size_t)(rloc + (half << 6)) * 64 + cbase;
        #pragma unroll
        for (int j = 0; j < 4; ++j) { o[j] = acc[0][j]; o[64 + j] = acc[1][j]; }
    };

    // stage2: N <- epilogue(GEMM(Tb_half, Q)) ; mode 0: lam*outer(u)+(1-lam)*acc
    //         mode 1: acc ; mode 2: lam*N + (1-lam)*acc
    auto stage2 = [&](const float* Qg, int mode, const float* u) {
        const float* Pb = Tb + (size_t)(half << 12) + rloc;   // 4096*half
        float acc[2][4];
        gemm64(Pb, Qg + cbase, acc);
        float* Nbase = half ? Ni : Nr;
        if (mode == 0) {
            float urc[4], uic[4];
            #pragma unroll
            for (int j = 0; j < 4; ++j) { urc[j] = u[cbase + j]; uic[j] = u[64 + cbase + j]; }
            #pragma unroll
            for (int i = 0; i < 2; ++i) {
                int r = rloc + i;
                float ur_ = u[r], ui_ = u[64 + r];
                #pragma unroll
                for (int j = 0; j < 4; ++j) {
                    float ov = half ? (ui_ * urc[j] - ur_ * uic[j])
                                    : (ur_ * urc[j] + ui_ * uic[j]);
                    Nbase[r * 64 + cbase + j] = lam * ov + (1.f - lam) * acc[i][j];
                }
            }
        } else if (mode == 1) {
            #pragma unroll
            for (int i = 0; i < 2; ++i)
                #pragma unroll
                for (int j = 0; j < 4; ++j)
                    Nbase[(rloc + i) * 64 + cbase + j] = acc[i][j];
        } else {
            #pragma unroll
            for (int i = 0; i < 2; ++i)
                #pragma unroll
                for (int j = 0; j < 4; ++j) {
                    int idx = (rloc + i) * 64 + cbase + j;
                    Nbase[idx] = lam * Nbase[idx] + (1.f - lam) * acc[i][j];
                }
        }
    };

    // square N (complex, Hermitian) -> h ; then trace-normalize + beta-mix with N
    auto square_into = [&](float* oR, float* oI) {
        const float* Pb = (half ? Ni : Nr) + rloc;
        float acc[2][4];
        gemm64(Pb, Nr + cbase, acc);   // SQ1: top=nr*nr, bottom=-(ni*nr)
        #pragma unroll
        for (int i = 0; i < 2; ++i)
            #pragma unroll
            for (int j = 0; j < 4; ++j) {
                int idx = (rloc + i) * 64 + cbase + j;
                if (!half) oR[idx] = acc[i][j];
                else       oI[idx] = -acc[i][j];
            }
        __syncthreads();
        gemm64(Pb, Ni + cbase, acc);   // SQ2: top=nr*ni, bottom=-(ni*ni)
        #pragma unroll
        for (int i = 0; i < 2; ++i)
            #pragma unroll
            for (int j = 0; j < 4; ++j) {
                int idx = (rloc + i) * 64 + cbase + j;
                if (!half) oI[idx] += acc[i][j];
                else       oR[idx] += acc[i][j];
            }
        __syncthreads();
        if (tid < 64) {
            float v = oR[tid * 64 + tid];
            v = wave_sum(v);
            if (tid == 0) scr[12] = v;
        }
        __syncthreads();
        const float sb = BETA_ / scr[12];
        const float cb = 1.0f - BETA_;
        for (int i = tid; i < 4096; i += 1024) {
            oR[i] = fmaf(sb, oR[i], cb * Nr[i]);
            oI[i] = fmaf(sb, oI[i], cb * Ni[i]);
        }
        __syncthreads();
    };

    for (int t = 0; t < T_; ++t) {
        const float* u = u_in + ((size_t)t * B_ + b) * 128;
        // ---- layer 1 (ux is rank-1 outer of u) ----
        stage1(h1r, h1i, UhT_g); __syncthreads();
        stage2(UhT_g, 0, u);     __syncthreads();
        square_into(h1r, h1i);   // h1 now = layer-1 output = x2
        // ---- layer 2 ----
        stage1(h1r, h1i, UxT_g); __syncthreads();   // ux-conj of x2
        stage2(UxT_g, 1, u);     __syncthreads();   // N = ux2
        stage1(h2r, h2i, UhT_g); __syncthreads();   // uh-conj of h2
        stage2(UhT_g, 2, u);     __syncthreads();   // N = lam*ux2 + (1-lam)*uh2
        square_into(h2r, h2i);
        // ---- dense + measurement: Z = [h2r|h2i]^T-stacked @ AB2  (128 x 32) ----
        {
            const int mr = tid >> 3;
            const int mc = (tid & 7) << 2;
            const int mhalf = mr >> 6;
            const int mrl = mr & 63;
            const float* Pb = (mhalf ? h2i : h2r) + mrl;
            const float* Qb = AB2_g + mc;
            float a0 = 0, a1 = 0, a2 = 0, a3 = 0;
            #pragma unroll 8
            for (int k = 0; k < 64; ++k) {
                float pv = Pb[(size_t)k * 64];
                float4 qv = *reinterpret_cast<const float4*>(Qb + (size_t)k * 32);
                a0 = fmaf(pv, qv.x, a0); a1 = fmaf(pv, qv.y, a1);
                a2 = fmaf(pv, qv.z, a2); a3 = fmaf(pv, qv.w, a3);
            }
            float* zp = Tb + (size_t)mr * 64 + mc;
            zp[0] = a0; zp[1] = a1; zp[2] = a2; zp[3] = a3;
        }
        __syncthreads();
        // q_k (waves 0..9) and tr(sigma) (wave 10)
        {
            const int wv = tid >> 6, ln = tid & 63;
            if (wv < 10) {
                float av = AB2_g[ln * 32 + wv];
                float bv = AB2_g[ln * 32 + 10 + wv];
                float z1a = Tb[ln * 64 + wv];
                float z1b = Tb[ln * 64 + 10 + wv];
                float z2a = Tb[(64 + ln) * 64 + wv];
                float z2b = Tb[(64 + ln) * 64 + 10 + wv];
                float v = av * z1a + bv * z1b + av * z2b - bv * z2a;
                v = wave_sum(v);
                if (ln == 0) scr[wv] = v;
            } else if (wv == 10) {
                float v = 0.f;
                #pragma unroll
                for (int c = 0; c < 10; ++c)
                    v = fmaf(W_g[ln * 10 + c], Tb[ln * 64 + 20 + c], v);
                v = wave_sum(v);
                if (ln == 0) scr[10] = v;
            }
        }
        __syncthreads();
        if (tid < 10) {
            float p = (dlam * scr[tid] + (1.f - dlam) * 0.1f) /
                      (dlam * scr[10] + (1.f - dlam));
            out[((size_t)b * T_ + t) * C_ + tid] = logf(p);
        }
        __syncthreads();
    }
}

extern "C" void kernel_launch(void* const* d_in, const int* in_sizes, int n_in,
                              void* d_out, int out_size, void* d_ws, size_t ws_size,
                              hipStream_t stream) {
    const float* x       = (const float*)d_in[0];
    const float* amp_w   = (const float*)d_in[1];
    const float* amp_b   = (const float*)d_in[2];
    const float* phase_w = (const float*)d_in[3];
    const float* phase_b = (const float*)d_in[4];
    const float* Ux      = (const float*)d_in[5];
    const float* Uh      = (const float*)d_in[6];
    const float* cl      = (const float*)d_in[7];
    const float* W       = (const float*)d_in[8];
    const float* dl      = (const float*)d_in[9];
    const float* meas    = (const float*)d_in[10];

    float* ws  = (float*)d_ws;
    float* u   = ws;                               // T*B*128 = 1,048,576 floats
    float* UhT = ws + (size_t)T_ * B_ * 128;       // 4096
    float* UxT = UhT + 4096;                       // 4096
    float* AB2 = UxT + 4096;                       // 2048
    float* out = (float*)d_out;

    proj_kernel<<<B_ * T_, 64, 0, stream>>>(x, amp_w, amp_b, phase_w, phase_b, Ux, u);
    setup_kernel<<<1, 256, 0, stream>>>(Uh, Ux, W, meas, UhT, UxT, AB2);
    qrnn_kernel<<<B_, 1024, 0, stream>>>(u, UhT, UxT, AB2, W, cl, dl, out);
}

// Round 2
// 1707.199 us; speedup vs baseline: 5.2811x; 5.2811x over previous
//
#include <hip/hip_runtime.h>
#include <math.h>

#define B_ 64
#define T_ 128
#define INDIM 300
#define D_ 64
#define C_ 10
#define BETA_ 0.8f

typedef unsigned int u32;
typedef _Float16 half8 __attribute__((ext_vector_type(8)));
typedef float f32x4 __attribute__((ext_vector_type(4)));
typedef u32 u32x4 __attribute__((ext_vector_type(4)));
typedef u32 u32x2 __attribute__((ext_vector_type(2)));

// fragment-group index: cb = 16-col block of the logical matrix, kc = 32-row (k) block
#define GIDX(cb,kc,ln) ((((cb)*2+(kc))*64) + (ln))

static __device__ __forceinline__ float sigmoidf_(float x){ return 1.f/(1.f+expf(-x)); }

static __device__ __forceinline__ float wave_sum(float v){
#pragma unroll
  for (int off = 32; off > 0; off >>= 1) v += __shfl_down(v, off);
  return v;
}

static __device__ __forceinline__ u32 pkh(_Float16 a, _Float16 b){
  unsigned short ba = __builtin_bit_cast(unsigned short, a);
  unsigned short bb = __builtin_bit_cast(unsigned short, b);
  return (u32)ba | ((u32)bb << 16);
}

// exact-ish fp32 -> (hi,lo) f16 split, RNE both: residual ~2^-24 * |x|
static __device__ __forceinline__ void split4(const float* x, u32x2& hw, u32x2& lw){
  _Float16 h0=(_Float16)x[0], h1=(_Float16)x[1], h2=(_Float16)x[2], h3=(_Float16)x[3];
  _Float16 l0=(_Float16)(x[0]-(float)h0), l1=(_Float16)(x[1]-(float)h1);
  _Float16 l2=(_Float16)(x[2]-(float)h2), l3=(_Float16)(x[3]-(float)h3);
  hw[0]=pkh(h0,h1); hw[1]=pkh(h2,h3); lw[0]=pkh(l0,l1); lw[1]=pkh(l2,l3);
}

static __device__ __forceinline__ void up2v(u32 hw, u32 lw, float& v0, float& v1){
  _Float16 h0=__builtin_bit_cast(_Float16,(unsigned short)(hw & 0xffffu));
  _Float16 h1=__builtin_bit_cast(_Float16,(unsigned short)(hw >> 16));
  _Float16 l0=__builtin_bit_cast(_Float16,(unsigned short)(lw & 0xffffu));
  _Float16 l1=__builtin_bit_cast(_Float16,(unsigned short)(lw >> 16));
  v0 = (float)h0 + (float)l0;
  v1 = (float)h1 + (float)l1;
}

static __device__ __forceinline__ void mfma4(half8 ah, half8 al, half8 bh, half8 bl, f32x4& acc){
  acc = __builtin_amdgcn_mfma_f32_16x16x32_f16(ah, bh, acc, 0, 0, 0);
  acc = __builtin_amdgcn_mfma_f32_16x16x32_f16(ah, bl, acc, 0, 0, 0);
  acc = __builtin_amdgcn_mfma_f32_16x16x32_f16(al, bh, acc, 0, 0, 0);
  acc = __builtin_amdgcn_mfma_f32_16x16x32_f16(al, bl, acc, 0, 0, 0);
}

// ---------------- Kernel A: projections + s + u = Ux @ s -------------------
__global__ __launch_bounds__(64) void proj_kernel(
    const float* __restrict__ x, const float* __restrict__ amp_w,
    const float* __restrict__ amp_b, const float* __restrict__ phase_w,
    const float* __restrict__ phase_b, const float* __restrict__ Ux,
    float* __restrict__ u_out) {
    __shared__ float xr[INDIM];
    __shared__ float s_r[D_], s_i[D_];
    const int bt = blockIdx.x;            // bt = b*T + t  (x is [B][T][IN])
    const int b = bt / T_, t = bt % T_;
    const float* xrow = x + (size_t)bt * INDIM;
    for (int i = threadIdx.x; i < INDIM; i += 64) xr[i] = xrow[i];
    __syncthreads();
    const int d = threadIdx.x;
    float a = amp_b[d], p = phase_b[d];
    for (int k = 0; k < INDIM; ++k) {
        float xv = xr[k];
        a = fmaf(xv, amp_w[k * D_ + d], a);
        p = fmaf(xv, phase_w[k * D_ + d], p);
    }
    float sq = a * a;
    #pragma unroll
    for (int off = 32; off > 0; off >>= 1) sq += __shfl_xor(sq, off);
    float an = a / sqrtf(sq);
    s_r[d] = an * cosf(p);
    s_i[d] = an * sinf(p);
    __syncthreads();
    float ur = 0.f, ui = 0.f;
    const float* Uxrow = Ux + d * D_;
    for (int e = 0; e < D_; ++e) {
        float uv = Uxrow[e];
        ur = fmaf(uv, s_r[e], ur);
        ui = fmaf(uv, s_i[e], ui);
    }
    float* ub = u_out + ((size_t)t * B_ + b) * 128;
    ub[d] = ur;
    ub[64 + d] = ui;
}

// ---------------- Kernel B: operand-fragment precompute --------------------
// UhFL/UxFL: Q = U^T in fragment layout, f16 hi/lo, group-of-8 words:
//   word index = (GIDX(cb,kc,lane))*8 + off; off<4 -> hi pair words, off>=4 -> lo
__global__ __launch_bounds__(256) void setup_kernel(
    const float* __restrict__ Uh, const float* __restrict__ Ux,
    const float* __restrict__ W, const float* __restrict__ meas,
    u32* __restrict__ UhFL, u32* __restrict__ UxFL,
    u32* __restrict__ AB2FL, float* __restrict__ AB2p)
{
  const int tid = threadIdx.x;
  for (int wi = tid; wi < 4096; wi += 256){
    int off = wi & 7, g = wi >> 3;
    int lane_ = g & 63, cbkc = g >> 6;
    int cb = cbkc >> 1, kc = cbkc & 1;
    int wq = off & 3; bool isHi = off < 4;
    int k0 = 32*kc + 8*(lane_>>4) + 2*wq;
    int c  = 16*cb + (lane_&15);
    {
      float x0 = Uh[c*64 + k0], x1 = Uh[c*64 + k0 + 1];     // Q[k][c] = Uh[c][k]
      _Float16 h0=(_Float16)x0, h1=(_Float16)x1;
      UhFL[wi] = isHi ? pkh(h0,h1)
                      : pkh((_Float16)(x0-(float)h0), (_Float16)(x1-(float)h1));
    }
    {
      float x0 = Ux[c*64 + k0], x1 = Ux[c*64 + k0 + 1];
      _Float16 h0=(_Float16)x0, h1=(_Float16)x1;
      UxFL[wi] = isHi ? pkh(h0,h1)
                      : pkh((_Float16)(x0-(float)h0), (_Float16)(x1-(float)h1));
    }
  }
  __shared__ float invn[C_];
  if (tid < C_) {
    float s = 0.f;
    for (int j = 0; j < C_; ++j) {
      float vr = meas[(tid * C_ + j) * 2], vi = meas[(tid * C_ + j) * 2 + 1];
      s += vr * vr + vi * vi;
    }
    invn[tid] = 1.0f / sqrtf(s);
  }
  __syncthreads();
  // AB2p[d][c] (row stride 32): c<10: a_c = W v̂r_c ; c<20: W v̂i ; c<30: W cols ; else 0
  for (int i = tid; i < D_ * 32; i += 256) {
    int dd = i >> 5, c = i & 31;
    float v = 0.f;
    if (c < C_) {
      float acc = 0.f;
      for (int j = 0; j < C_; ++j) acc = fmaf(W[dd * C_ + j], meas[(c * C_ + j) * 2], acc);
      v = acc * invn[c];
    } else if (c < 2 * C_) {
      int k = c - C_;
      float acc = 0.f;
      for (int j = 0; j < C_; ++j) acc = fmaf(W[dd * C_ + j], meas[(k * C_ + j) * 2 + 1], acc);
      v = acc * invn[k];
    } else if (c < 3 * C_) {
      v = W[dd * C_ + (c - 2 * C_)];
    }
    AB2p[i] = v;
  }
  __syncthreads();
  // AB2FL: Q[k][c] = AB2p[k][c], cb in {0,1}
  for (int wi = tid; wi < 2048; wi += 256){
    int off = wi & 7, g = wi >> 3;
    int lane_ = g & 63, cbkc = g >> 6;
    int cb = cbkc >> 1, kc = cbkc & 1;
    int wq = off & 3; bool isHi = off < 4;
    int k0 = 32*kc + 8*(lane_>>4) + 2*wq;
    int c  = 16*cb + (lane_&15);
    float x0 = AB2p[k0*32 + c], x1 = AB2p[(k0+1)*32 + c];
    _Float16 h0=(_Float16)x0, h1=(_Float16)x1;
    AB2FL[wi] = isHi ? pkh(h0,h1)
                     : pkh((_Float16)(x0-(float)h0), (_Float16)(x1-(float)h1));
  }
}

// ---------------- Kernel C: fused 2-layer scan + dense + measurement -------
__global__ __launch_bounds__(512) void qrnn_kernel(
    const float* __restrict__ u_in,
    const u32* __restrict__ UhFL, const u32* __restrict__ UxFL,
    const u32* __restrict__ AB2FL, const float* __restrict__ AB2p,
    const float* __restrict__ W_g,
    const float* __restrict__ cell_lambda, const float* __restrict__ dense_lambda,
    float* __restrict__ out)
{
  // 8 matrix buffers, each 4096 u32 (hi-plane 2048 | lo-plane 2048)
  __shared__ __align__(16) u32 ds[8*4096];
  __shared__ float u_lds[128];
  __shared__ float scr[16];

  const int tid = threadIdx.x;
  const int lane = tid & 63;
  const int w = tid >> 6;
  const int h = lane >> 4;
  const int c15 = lane & 15;
  const int bidx = blockIdx.x;
  const float lam = sigmoidf_(cell_lambda[0]);
  const float dlam = sigmoidf_(dense_lambda[0]);

  u32* H1R = ds + 0*4096; u32* H1I = ds + 1*4096;
  u32* H2R = ds + 2*4096; u32* H2I = ds + 3*4096;
  u32* NR  = ds + 4*4096; u32* NI  = ds + 5*4096;
  u32* TR  = ds + 6*4096; u32* TI  = ds + 7*4096;
  float* Z = reinterpret_cast<float*>(TR);   // 128x33 fp32 = 16896 B, fits TR+TI

  // ---- static U operand fragments pinned in registers (128 VGPR) ----
  u32x4 uhh[8], uhl[8], uxh[8], uxl[8];
#pragma unroll
  for (int g = 0; g < 8; ++g){
    const u32* p = UhFL + (size_t)(g*64 + lane)*8;
    uhh[g] = *reinterpret_cast<const u32x4*>(p);
    uhl[g] = *reinterpret_cast<const u32x4*>(p+4);
    const u32* q = UxFL + (size_t)(g*64 + lane)*8;
    uxh[g] = *reinterpret_cast<const u32x4*>(q);
    uxl[g] = *reinterpret_cast<const u32x4*>(q+4);
  }

  // ---- init h1 = h2 = I/64 (f16-exact: lo plane = 0) ----
  const u32 one64 = (u32)__builtin_bit_cast(unsigned short, (_Float16)0.015625f);
  for (int wi = tid; wi < 4096; wi += 512){
    u32 vR = 0u;
    if (wi < 2048){
      int g = wi >> 2, wq = wi & 3;
      int lane_ = g & 63, cbkc = g >> 6;
      int cb = cbkc >> 1, kc = cbkc & 1;
      int k0 = 32*kc + 8*(lane_>>4) + 2*wq;
      int c = 16*cb + (lane_&15);
      if (k0 == c)   vR |= one64;
      if (k0+1 == c) vR |= (one64 << 16);
    }
    H1R[wi] = vR; H2R[wi] = vR; H1I[wi] = 0u; H2I[wi] = 0u;
  }
  __syncthreads();

  auto ldfrag = [&](const u32* buf, int g, half8& fh, half8& fl, bool neg){
    u32x4 a = *reinterpret_cast<const u32x4*>(buf + g*4);
    u32x4 b = *reinterpret_cast<const u32x4*>(buf + 2048 + g*4);
    if (neg){
#pragma unroll
      for (int i=0;i<4;++i){ a[i]^=0x80008000u; b[i]^=0x80008000u; }
    }
    fh = __builtin_bit_cast(half8, a);
    fl = __builtin_bit_cast(half8, b);
  };

  // one 64x64 GEMM pair (R,I): waves 0-3 compute R (ti=w&3), 4-7 compute I
  // mode 0: plain; 1: N = lam*outer(u) + (1-lam)*acc; 2: N = lam*N + (1-lam)*acc
  auto stageU = [&](const u32* AR, const u32* AI, u32* OR_, u32* OI_, int mode, bool useUx){
    const int comp = w >> 2;
    const int ti = w & 3;
    const u32* A = comp ? AI : AR;
    u32* O = comp ? OI_ : OR_;
    half8 ah[2], al[2];
#pragma unroll
    for (int kc=0; kc<2; ++kc) ldfrag(A, GIDX(ti,kc,lane), ah[kc], al[kc], false);
    f32x4 acc[4];
#pragma unroll
    for (int tj=0;tj<4;++tj) acc[tj] = f32x4{0.f,0.f,0.f,0.f};
#pragma unroll
    for (int tj=0;tj<4;++tj){
#pragma unroll
      for (int kc=0;kc<2;++kc){
        u32x4 bhw = useUx ? uxh[tj*2+kc] : uhh[tj*2+kc];
        u32x4 blw = useUx ? uxl[tj*2+kc] : uhl[tj*2+kc];
        mfma4(ah[kc], al[kc], __builtin_bit_cast(half8,bhw),
              __builtin_bit_cast(half8,blw), acc[tj]);
      }
    }
    float urr[4], uir[4];
    if (mode == 1){
#pragma unroll
      for (int rr=0;rr<4;++rr){
        urr[rr] = u_lds[16*ti + 4*h + rr];
        uir[rr] = u_lds[64 + 16*ti + 4*h + rr];
      }
    }
    const int s = h & 1;
    const int lp = c15 + 16*((2*ti + (h>>1)) & 3);
#pragma unroll
    for (int tj=0;tj<4;++tj){
      const int g = GIDX(tj, ti>>1, lp);
      float x[4];
#pragma unroll
      for (int rr=0;rr<4;++rr) x[rr] = acc[tj][rr];
      if (mode == 1){
        float urc = u_lds[16*tj + c15], uic = u_lds[64 + 16*tj + c15];
#pragma unroll
        for (int rr=0;rr<4;++rr){
          float ov = comp ? (uir[rr]*urc - urr[rr]*uic) : (urr[rr]*urc + uir[rr]*uic);
          x[rr] = lam*ov + (1.f-lam)*x[rr];
        }
      } else if (mode == 2){
        u32x2 nh = *reinterpret_cast<const u32x2*>(O + g*4 + 2*s);
        u32x2 nl = *reinterpret_cast<const u32x2*>(O + 2048 + g*4 + 2*s);
        float n0,n1,n2,n3; up2v(nh[0],nl[0],n0,n1); up2v(nh[1],nl[1],n2,n3);
        x[0]=lam*n0+(1.f-lam)*x[0]; x[1]=lam*n1+(1.f-lam)*x[1];
        x[2]=lam*n2+(1.f-lam)*x[2]; x[3]=lam*n3+(1.f-lam)*x[3];
      }
      u32x2 hw, lw; split4(x, hw, lw);
      *reinterpret_cast<u32x2*>(O + g*4 + 2*s) = hw;
      *reinterpret_cast<u32x2*>(O + 2048 + g*4 + 2*s) = lw;
    }
  };

  // complex Hermitian square + trace-normalize + beta-mix: (NR,NI) -> (oR,oI)
  auto sqstep = [&](const u32* NRb, const u32* NIb, u32* oRb, u32* oIb){
    const int o = w >> 2;          // 0: real output, 1: imag output
    const int a = (w >> 1) & 1;    // ti block
    const int bb = w & 1;          // tj block
    f32x4 acc[2][2];
#pragma unroll
    for (int i=0;i<2;++i)
#pragma unroll
      for (int j=0;j<2;++j) acc[i][j] = f32x4{0.f,0.f,0.f,0.f};
#pragma unroll
    for (int m=0;m<2;++m){
      const u32* Ab = m ? NIb : NRb;
      const u32* Bb = o ? (m ? NRb : NIb) : (m ? NIb : NRb);
      const bool neg = (o==1) && (m==1);
#pragma unroll
      for (int kc=0;kc<2;++kc){
        half8 ah[2],al[2],bh[2],bl[2];
#pragma unroll
        for (int i=0;i<2;++i){
          ldfrag(Ab, GIDX(2*a+i,  kc, lane), ah[i], al[i], neg);
          ldfrag(Bb, GIDX(2*bb+i, kc, lane), bh[i], bl[i], false);
        }
#pragma unroll
        for (int i=0;i<2;++i)
#pragma unroll
          for (int j=0;j<2;++j)
            mfma4(ah[i],al[i],bh[j],bl[j],acc[i][j]);
      }
    }
    // trace of raw real square (diag tiles live in waves 0 and 3)
    if (o==0 && a==bb){
      float dv = 0.f;
      if ((c15>>2) == h){
        const int rr = c15 & 3;
        dv = acc[0][0][rr] + acc[1][1][rr];
      }
      dv = wave_sum(dv);
      if (lane == 0) scr[a] = dv;
    }
    __syncthreads();
    const float trv = scr[0] + scr[1];
    const float sb = BETA_ / trv;
    const float cbm = 1.f - BETA_;
    const u32* Nsrc = o ? NIb : NRb;
    u32* Od = o ? oIb : oRb;
    const int s = h & 1;
#pragma unroll
    for (int i=0;i<2;++i){
      const int tig = 2*a+i;
      const int lp = c15 + 16*((2*tig + (h>>1)) & 3);
#pragma unroll
      for (int j=0;j<2;++j){
        const int tjg = 2*bb+j;
        const int g = GIDX(tjg, tig>>1, lp);
        u32x2 nh = *reinterpret_cast<const u32x2*>(Nsrc + g*4 + 2*s);
        u32x2 nl = *reinterpret_cast<const u32x2*>(Nsrc + 2048 + g*4 + 2*s);
        float n0,n1,n2,n3; up2v(nh[0],nl[0],n0,n1); up2v(nh[1],nl[1],n2,n3);
        float x[4] = { sb*acc[i][j][0] + cbm*n0, sb*acc[i][j][1] + cbm*n1,
                       sb*acc[i][j][2] + cbm*n2, sb*acc[i][j][3] + cbm*n3 };
        u32x2 hw, lw; split4(x, hw, lw);
        *reinterpret_cast<u32x2*>(Od + g*4 + 2*s) = hw;
        *reinterpret_cast<u32x2*>(Od + 2048 + g*4 + 2*s) = lw;
      }
    }
    __syncthreads();
  };

  for (int t = 0; t < T_; ++t){
    if (tid < 128) u_lds[tid] = u_in[((size_t)t*B_ + bidx)*128 + tid];
    stageU(H1R,H1I, TR,TI, 0, false); __syncthreads();   // T = conj-half(h1, Uh)
    stageU(TR,TI,  NR,NI, 1, false);  __syncthreads();   // N = lam*outer(u)+(1-lam)*uh(h1)
    sqstep(NR,NI, H1R,H1I);                              // h1 = activation(N)
    stageU(H1R,H1I, TR,TI, 0, true);  __syncthreads();   // layer 2: ux path
    stageU(TR,TI,  NR,NI, 0, true);   __syncthreads();   // N = ux(x2)
    stageU(H2R,H2I, TR,TI, 0, false); __syncthreads();   // uh path on h2
    stageU(TR,TI,  NR,NI, 2, false);  __syncthreads();   // N = lam*N + (1-lam)*uh(h2)
    sqstep(NR,NI, H2R,H2I);                              // h2 = activation(N)

    // ---- dense: Z[128][32] = stacked(h2)^T-ish @ AB2 (fragment GEMM) ----
    {
      const u32* src = (w >= 4) ? H2I : H2R;
      const int cb = w & 3;
      half8 ah[2], al[2];
      ldfrag(src, GIDX(cb,0,lane), ah[0], al[0], false);
      ldfrag(src, GIDX(cb,1,lane), ah[1], al[1], false);
      f32x4 zacc[2];
      zacc[0] = f32x4{0.f,0.f,0.f,0.f}; zacc[1] = f32x4{0.f,0.f,0.f,0.f};
#pragma unroll
      for (int tj=0;tj<2;++tj)
#pragma unroll
        for (int kc=0;kc<2;++kc){
          const u32* p = AB2FL + (size_t)((tj*2+kc)*64 + lane)*8;
          u32x4 b0 = *reinterpret_cast<const u32x4*>(p);
          u32x4 b1 = *reinterpret_cast<const u32x4*>(p+4);
          mfma4(ah[kc], al[kc], __builtin_bit_cast(half8,b0),
                __builtin_bit_cast(half8,b1), zacc[tj]);
        }
#pragma unroll
      for (int tj=0;tj<2;++tj)
#pragma unroll
        for (int rr=0;rr<4;++rr)
          Z[(size_t)(16*w + 4*h + rr)*33 + 16*tj + c15] = zacc[tj][rr];
    }
    __syncthreads();

    // ---- measurement reductions ----
    {
      const int k = w;  // waves 0..7 -> q_0..q_7
      float av = AB2p[lane*32 + k], bv = AB2p[lane*32 + 10 + k];
      float v = av*Z[lane*33 + k] + bv*Z[lane*33 + 10 + k]
              + av*Z[(64+lane)*33 + 10 + k] - bv*Z[(64+lane)*33 + k];
      v = wave_sum(v);
      if (lane == 0) scr[k] = v;
      if (w < 2){
        const int k2 = 8 + w;
        float av2 = AB2p[lane*32 + k2], bv2 = AB2p[lane*32 + 10 + k2];
        float v2 = av2*Z[lane*33 + k2] + bv2*Z[lane*33 + 10 + k2]
                 + av2*Z[(64+lane)*33 + 10 + k2] - bv2*Z[(64+lane)*33 + k2];
        v2 = wave_sum(v2);
        if (lane == 0) scr[k2] = v2;
      } else if (w == 2){
        float v2 = 0.f;
#pragma unroll
        for (int cc=0; cc<10; ++cc)
          v2 = fmaf(W_g[lane*10 + cc], Z[lane*33 + 20 + cc], v2);
        v2 = wave_sum(v2);
        if (lane == 0) scr[10] = v2;
      }
    }
    __syncthreads();
    if (tid < 10){
      float p = (dlam*scr[tid] + (1.f-dlam)*0.1f) / (dlam*scr[10] + (1.f-dlam));
      out[((size_t)bidx*T_ + t)*C_ + tid] = logf(p);
    }
    __syncthreads();
  }
}

extern "C" void kernel_launch(void* const* d_in, const int* in_sizes, int n_in,
                              void* d_out, int out_size, void* d_ws, size_t ws_size,
                              hipStream_t stream) {
    const float* x       = (const float*)d_in[0];
    const float* amp_w   = (const float*)d_in[1];
    const float* amp_b   = (const float*)d_in[2];
    const float* phase_w = (const float*)d_in[3];
    const float* phase_b = (const float*)d_in[4];
    const float* Ux      = (const float*)d_in[5];
    const float* Uh      = (const float*)d_in[6];
    const float* cl      = (const float*)d_in[7];
    const float* W       = (const float*)d_in[8];
    const float* dl      = (const float*)d_in[9];
    const float* meas    = (const float*)d_in[10];

    float* ws   = (float*)d_ws;
    float* u    = ws;                                  // 128*64*128 = 1,048,576 f32
    u32*  UhFL  = (u32*)(ws + 1048576);                // 4096
    u32*  UxFL  = UhFL + 4096;                         // 4096
    u32*  AB2FL = UxFL + 4096;                         // 2048
    float* AB2p = (float*)(AB2FL + 2048);              // 2048
    float* out  = (float*)d_out;

    proj_kernel<<<B_ * T_, 64, 0, stream>>>(x, amp_w, amp_b, phase_w, phase_b, Ux, u);
    setup_kernel<<<1, 256, 0, stream>>>(Uh, Ux, W, meas, UhFL, UxFL, AB2FL, AB2p);
    qrnn_kernel<<<B_, 512, 0, stream>>>(u, UhFL, UxFL, AB2FL, AB2p, W, cl, dl, out);
}